// Round 5
// baseline (2059.528 us; speedup 1.0000x reference)
//
#include <hip/hip_runtime.h>
#include <hip/hip_bf16.h>

typedef __bf16 bf16_t;
typedef __bf16 bf16x8 __attribute__((ext_vector_type(8)));
typedef __bf16 bf16x4 __attribute__((ext_vector_type(4)));
typedef float f32x4 __attribute__((ext_vector_type(4)));

#define MFMA16(a, b, c) __builtin_amdgcn_mfma_f32_16x16x32_bf16((a), (b), (c), 0, 0, 0)

// load 8 consecutive f32, round to bf16x8 (RNE)
__device__ inline bf16x8 cvt8(const float* __restrict__ p) {
    f32x4 a = *reinterpret_cast<const f32x4*>(p);
    f32x4 b = *reinterpret_cast<const f32x4*>(p + 4);
    bf16x8 r;
    r[0] = (bf16_t)a[0]; r[1] = (bf16_t)a[1]; r[2] = (bf16_t)a[2]; r[3] = (bf16_t)a[3];
    r[4] = (bf16_t)b[0]; r[5] = (bf16_t)b[1]; r[6] = (bf16_t)b[2]; r[7] = (bf16_t)b[3];
    return r;
}

// ---------------------------------------------------------------------------
// f32 -> bf16 elementwise (weight pre-convert), 4 elems/thread
// ---------------------------------------------------------------------------
__global__ __launch_bounds__(256) void cvt_f32_bf16(
    const float* __restrict__ in, bf16_t* __restrict__ out, int n4)
{
    int i = blockIdx.x * 256 + threadIdx.x;
    if (i < n4) {
        f32x4 v = reinterpret_cast<const f32x4*>(in)[i];
        bf16x4 r;
        r[0] = (bf16_t)v[0]; r[1] = (bf16_t)v[1];
        r[2] = (bf16_t)v[2]; r[3] = (bf16_t)v[3];
        reinterpret_cast<bf16x4*>(out)[i] = r;
    }
}

// ---------------------------------------------------------------------------
// Projection: out[M,512] = bf16(X[M,K]) @ bf16(W[512,K])^T + bias, opt L2 norm.
// f32 output (+ optional bf16 mirror for the maxsim stage).
// Block = 256 thr (4 waves) = 16 rows x 512 cols. Wave w: cols w*128..+127.
// MFMA 16x16x32 bf16 C/D map (HW-confirmed by round-3 probe, bit-identical):
// row = quad*4 + reg, col = lane&15; identity k-pairing.
// ---------------------------------------------------------------------------
template <bool WB>
__global__ __launch_bounds__(256) void proj_kernel(
    const float* __restrict__ A,     // [M, K] f32
    const void*  __restrict__ Wp,    // [512, K] bf16 (WB) or f32 (!WB)
    const float* __restrict__ bias,  // [512] f32
    float* __restrict__ out,         // [M, 512] f32
    bf16_t* __restrict__ outb,       // [M, 512] bf16 mirror or nullptr
    int K, int do_l2)
{
    const int tid  = threadIdx.x;
    const int wave = tid >> 6;
    const int lane = tid & 63;
    const int l16  = lane & 15;
    const int quad = lane >> 4;
    const int m0   = blockIdx.x * 16;
    const int e0   = wave * 128;

    f32x4 acc[8];
#pragma unroll
    for (int t = 0; t < 8; ++t) acc[t] = (f32x4){0.f, 0.f, 0.f, 0.f};

    const float* arow = A + (size_t)(m0 + l16) * K + quad * 8;
    const bf16_t* wb = (const bf16_t*)Wp;
    const float*  wf = (const float*)Wp;

    for (int k0 = 0; k0 < K; k0 += 32) {
        bf16x8 af = cvt8(arow + k0);
#pragma unroll
        for (int t = 0; t < 8; ++t) {
            const size_t roff = (size_t)(e0 + t * 16 + l16) * K + quad * 8 + k0;
            bf16x8 bfv;
            if constexpr (WB) bfv = *reinterpret_cast<const bf16x8*>(wb + roff);
            else              bfv = cvt8(wf + roff);
            acc[t] = MFMA16(af, bfv, acc[t]);
        }
    }

    // bias add (per-column e; lane's column = l16, fixed across regs)
#pragma unroll
    for (int t = 0; t < 8; ++t) {
        float bv = bias[e0 + t * 16 + l16];
#pragma unroll
        for (int r = 0; r < 4; ++r) acc[t][r] += bv;
    }

    float inv[4] = {1.f, 1.f, 1.f, 1.f};
    __shared__ float sq[4][16];
    if (do_l2) {
#pragma unroll
        for (int r = 0; r < 4; ++r) {
            float s = 0.f;
#pragma unroll
            for (int t = 0; t < 8; ++t) s += acc[t][r] * acc[t][r];
            s += __shfl_xor(s, 1);
            s += __shfl_xor(s, 2);
            s += __shfl_xor(s, 4);
            s += __shfl_xor(s, 8);
            if (l16 == 0) sq[wave][quad * 4 + r] = s;  // this wave's 128-col partial
        }
        __syncthreads();
#pragma unroll
        for (int r = 0; r < 4; ++r) {
            int row = quad * 4 + r;
            float tot = sq[0][row] + sq[1][row] + sq[2][row] + sq[3][row];
            inv[r] = 1.0f / fmaxf(sqrtf(tot), 1e-12f);
        }
    }

#pragma unroll
    for (int t = 0; t < 8; ++t)
#pragma unroll
        for (int r = 0; r < 4; ++r) {
            const size_t o = (size_t)(m0 + quad * 4 + r) * 512 + (e0 + t * 16 + l16);
            float val = acc[t][r] * inv[r];
            out[o] = val;
            if (outb) outb[o] = (bf16_t)val;
        }
}

// ---------------------------------------------------------------------------
// MaxSim: block per (b,q). S[t,v] = te[b,t,:] . ve[q,v,:], T=64, V=196, K=512.
// Wave w: t rows 16w..16w+15, 13 v-tiles (v>=196 clamped on load, masked in
// reductions). BF: operands already bf16 (ws mirror) vs f32 (convert on load).
// sim f32 output.
// ---------------------------------------------------------------------------
template <bool BF>
__global__ __launch_bounds__(256) void maxsim_kernel(
    const void* __restrict__ te_,  // [128,64,512]
    const void* __restrict__ ve_,  // [128,196,512]
    float* __restrict__ sim)       // [128,128] (b major)
{
    const int tid  = threadIdx.x;
    const int wave = tid >> 6;
    const int lane = tid & 63;
    const int l16  = lane & 15;
    const int quad = lane >> 4;
    const int b    = blockIdx.x & 127;
    const int q    = blockIdx.x >> 7;

    const bf16_t* teb = (const bf16_t*)te_;
    const float*  tef = (const float*)te_;
    const bf16_t* veb = (const bf16_t*)ve_;
    const float*  vef = (const float*)ve_;

    f32x4 acc[13];
#pragma unroll
    for (int vt = 0; vt < 13; ++vt) acc[vt] = (f32x4){0.f, 0.f, 0.f, 0.f};

    const size_t toff = ((size_t)b * 64 + wave * 16 + l16) * 512 + quad * 8;
    size_t voff[13];
#pragma unroll
    for (int vt = 0; vt < 13; ++vt) {
        int v = vt * 16 + l16;
        if (v > 195) v = 195;  // clamped load; masked out of reductions below
        voff[vt] = ((size_t)q * 196 + v) * 512 + quad * 8;
    }

    for (int k0 = 0; k0 < 512; k0 += 32) {
        bf16x8 af;
        if constexpr (BF) af = *reinterpret_cast<const bf16x8*>(teb + toff + k0);
        else              af = cvt8(tef + toff + k0);
#pragma unroll
        for (int vt = 0; vt < 13; ++vt) {
            bf16x8 bfv;
            if constexpr (BF) bfv = *reinterpret_cast<const bf16x8*>(veb + voff[vt] + k0);
            else              bfv = cvt8(vef + voff[vt] + k0);
            acc[vt] = MFMA16(af, bfv, acc[vt]);
        }
    }

    __shared__ float maxt_s[4][208];
    __shared__ float t2v_part[4];

    // ---- t2v: per t-row (row = quad*4+r of this wave) max over v, sum over t
    float sum_maxv = 0.f;
#pragma unroll
    for (int r = 0; r < 4; ++r) {
        float m = -3.0e38f;
#pragma unroll
        for (int vt = 0; vt < 13; ++vt) {
            int v = vt * 16 + l16;
            if (v < 196) m = fmaxf(m, acc[vt][r]);
        }
        m = fmaxf(m, __shfl_xor(m, 1));
        m = fmaxf(m, __shfl_xor(m, 2));
        m = fmaxf(m, __shfl_xor(m, 4));
        m = fmaxf(m, __shfl_xor(m, 8));
        sum_maxv += m;  // this quad's t-row r (uniform across the quad's 16 lanes)
    }
    sum_maxv += __shfl_xor(sum_maxv, 16);  // sum the 4 quads (4 rows each)
    sum_maxv += __shfl_xor(sum_maxv, 32);
    if (lane == 0) t2v_part[wave] = sum_maxv;

    // ---- v2t: per v (col = l16 of tile vt) max over this wave's 16 t rows
#pragma unroll
    for (int vt = 0; vt < 13; ++vt) {
        float m = fmaxf(fmaxf(acc[vt][0], acc[vt][1]),
                        fmaxf(acc[vt][2], acc[vt][3]));
        m = fmaxf(m, __shfl_xor(m, 16));
        m = fmaxf(m, __shfl_xor(m, 32));
        if (lane < 16) maxt_s[wave][vt * 16 + l16] = m;
    }
    __syncthreads();

    if (wave == 0) {
        float s_row = t2v_part[0] + t2v_part[1] + t2v_part[2] + t2v_part[3];
        float s_col = 0.f;
        for (int v = lane; v < 196; v += 64) {
            float m = fmaxf(fmaxf(maxt_s[0][v], maxt_s[1][v]),
                            fmaxf(maxt_s[2][v], maxt_s[3][v]));
            s_col += m;
        }
        s_col += __shfl_xor(s_col, 1);
        s_col += __shfl_xor(s_col, 2);
        s_col += __shfl_xor(s_col, 4);
        s_col += __shfl_xor(s_col, 8);
        s_col += __shfl_xor(s_col, 16);
        s_col += __shfl_xor(s_col, 32);
        if (lane == 0) {
            float t2v = s_row * (1.0f / 196.0f);
            float v2t = s_col * (1.0f / 64.0f);
            sim[(size_t)b * 128 + q] = 0.5f * (t2v + v2t);
        }
    }
}

// ---------------------------------------------------------------------------
// text_mask[b,t] = (t < len[b]), f32 out. Lengths are 1..64 (never 0): int64
// storage shows hi-word==0 at odd i32 index -> auto-detect and stride.
// ---------------------------------------------------------------------------
__global__ void mask_kernel(const int* __restrict__ len, float* __restrict__ mask)
{
    int i = blockIdx.x * 256 + threadIdx.x;
    int is64 = (len[1] == 0) ? 1 : 0;
    if (i < 128 * 64) {
        int b = i >> 6;
        int t = i & 63;
        int L = is64 ? len[2 * b] : len[b];
        mask[i] = (t < L) ? 1.0f : 0.0f;
    }
}

extern "C" void kernel_launch(void* const* d_in, const int* in_sizes, int n_in,
                              void* d_out, int out_size, void* d_ws, size_t ws_size,
                              hipStream_t stream)
{
    // semantic -> d_in index; default = setup_inputs() dict order
    int idx[13] = {0, 1, 2, 3, 4, 5, 6, 7, 8, 9, 10, 11, 12};
    if (in_sizes && n_in >= 13) {
        bool dict = (in_sizes[2] == 19267584) && (in_sizes[4] == 393216);
        if (!dict) {
            static const int alpha_sizes[13] = {393216, 393216, 393216, 393216,
                                                512, 512, 512, 512, 128,
                                                98304, 6291456, 98304, 19267584};
            bool alpha = true;
            for (int i = 0; i < 13; ++i)
                if (in_sizes[i] != alpha_sizes[i]) { alpha = false; break; }
            if (alpha) {
                const int m[13] = {11, 9, 12, 10, 2, 6, 0, 4, 3, 7, 1, 5, 8};
                for (int i = 0; i < 13; ++i) idx[i] = m[i];
            }
        }
    }

    const float* visual_cls     = (const float*)d_in[idx[0]];
    const float* textual_cls    = (const float*)d_in[idx[1]];
    const float* visual_tokens  = (const float*)d_in[idx[2]];
    const float* textual_tokens = (const float*)d_in[idx[3]];
    const float* Wv_cls = (const float*)d_in[idx[4]];
    const float* bv_cls = (const float*)d_in[idx[5]];
    const float* Wt_cls = (const float*)d_in[idx[6]];
    const float* bt_cls = (const float*)d_in[idx[7]];
    const float* Wv_tok = (const float*)d_in[idx[8]];
    const float* bv_tok = (const float*)d_in[idx[9]];
    const float* Wt_tok = (const float*)d_in[idx[10]];
    const float* bt_tok = (const float*)d_in[idx[11]];
    const int*   text_length = (const int*)d_in[idx[12]];

    // f32 outputs, concatenated flat in return order
    float* out    = (float*)d_out;
    float* o_vcls = out;              // 128*512     = 65536
    float* o_tcls = out + 65536;      // 128*512     = 65536
    float* o_ve   = out + 131072;     // 128*196*512 = 12845056
    float* o_te   = out + 12976128;   // 128*64*512  = 4194304
    float* o_mask = out + 17170432;   // 128*64      = 8192
    float* o_sim  = out + 17178624;   // 128*128     = 16384

    const size_t WN  = (size_t)512 * 768;   // weight elems
    const size_t NVE = (size_t)12845056;    // ve elems
    const size_t NTE = (size_t)4194304;     // te elems
    const bool ws_w   = ws_size >= 4 * WN * sizeof(bf16_t);
    const bool ws_big = ws_size >= (4 * WN + NVE + NTE) * sizeof(bf16_t);

    bf16_t* w0 = (bf16_t*)d_ws;
    bf16_t* w1 = w0 + WN;
    bf16_t* w2 = w1 + WN;
    bf16_t* w3 = w2 + WN;
    bf16_t* b_ve = ws_big ? (w3 + WN) : nullptr;
    bf16_t* b_te = ws_big ? (w3 + WN + NVE) : nullptr;

    dim3 blk(256);
    if (ws_w) {
        const int n4 = (int)(WN / 4);       // 98304
        const int cvtg = (n4 + 255) / 256;  // 384
        cvt_f32_bf16<<<cvtg, blk, 0, stream>>>(Wv_cls, w0, n4);
        cvt_f32_bf16<<<cvtg, blk, 0, stream>>>(Wt_cls, w1, n4);
        cvt_f32_bf16<<<cvtg, blk, 0, stream>>>(Wv_tok, w2, n4);
        cvt_f32_bf16<<<cvtg, blk, 0, stream>>>(Wt_tok, w3, n4);

        proj_kernel<true><<<8, blk, 0, stream>>>(visual_cls,  w0, bv_cls, o_vcls, nullptr, 768, 0);
        proj_kernel<true><<<8, blk, 0, stream>>>(textual_cls, w1, bt_cls, o_tcls, nullptr, 768, 0);
        proj_kernel<true><<<1568, blk, 0, stream>>>(visual_tokens,  w2, bv_tok, o_ve, b_ve, 768, 1);
        proj_kernel<true><<<512,  blk, 0, stream>>>(textual_tokens, w3, bt_tok, o_te, b_te, 768, 1);
    } else {
        proj_kernel<false><<<8, blk, 0, stream>>>(visual_cls,  Wv_cls, bv_cls, o_vcls, nullptr, 768, 0);
        proj_kernel<false><<<8, blk, 0, stream>>>(textual_cls, Wt_cls, bt_cls, o_tcls, nullptr, 768, 0);
        proj_kernel<false><<<1568, blk, 0, stream>>>(visual_tokens,  Wv_tok, bv_tok, o_ve, nullptr, 768, 1);
        proj_kernel<false><<<512,  blk, 0, stream>>>(textual_tokens, Wt_tok, bt_tok, o_te, nullptr, 768, 1);
    }

    mask_kernel<<<32, blk, 0, stream>>>(text_length, o_mask);

    if (ws_big)
        maxsim_kernel<true><<<128 * 128, blk, 0, stream>>>(b_te, b_ve, o_sim);
    else
        maxsim_kernel<false><<<128 * 128, blk, 0, stream>>>(o_te, o_ve, o_sim);
}

// Round 6
// 1127.960 us; speedup vs baseline: 1.8259x; 1.8259x over previous
//
#include <hip/hip_runtime.h>
#include <hip/hip_bf16.h>

typedef __bf16 bf16_t;
typedef __bf16 bf16x8 __attribute__((ext_vector_type(8)));
typedef __bf16 bf16x4 __attribute__((ext_vector_type(4)));
typedef float f32x4 __attribute__((ext_vector_type(4)));

#define MFMA16(a, b, c) __builtin_amdgcn_mfma_f32_16x16x32_bf16((a), (b), (c), 0, 0, 0)

// load 8 consecutive f32, round to bf16x8 (RNE)
__device__ inline bf16x8 cvt8(const float* __restrict__ p) {
    f32x4 a = *reinterpret_cast<const f32x4*>(p);
    f32x4 b = *reinterpret_cast<const f32x4*>(p + 4);
    bf16x8 r;
    r[0] = (bf16_t)a[0]; r[1] = (bf16_t)a[1]; r[2] = (bf16_t)a[2]; r[3] = (bf16_t)a[3];
    r[4] = (bf16_t)b[0]; r[5] = (bf16_t)b[1]; r[6] = (bf16_t)b[2]; r[7] = (bf16_t)b[3];
    return r;
}

// ---------------------------------------------------------------------------
// f32 -> bf16 elementwise (weight pre-convert), 4 elems/thread
// ---------------------------------------------------------------------------
__global__ __launch_bounds__(256) void cvt_f32_bf16(
    const float* __restrict__ in, bf16_t* __restrict__ out, int n4)
{
    int i = blockIdx.x * 256 + threadIdx.x;
    if (i < n4) {
        f32x4 v = reinterpret_cast<const f32x4*>(in)[i];
        bf16x4 r;
        r[0] = (bf16_t)v[0]; r[1] = (bf16_t)v[1];
        r[2] = (bf16_t)v[2]; r[3] = (bf16_t)v[3];
        reinterpret_cast<bf16x4*>(out)[i] = r;
    }
}

// ---------------------------------------------------------------------------
// Projection: out[M,512] = bf16(X[M,768]) @ bf16(W[512,768])^T + bias,
// optional row L2-norm. f32 out + optional bf16 mirror.
// Block = 256 thr (4 waves) = 64 rows x 512 cols. Wave w: cols w*128..+127,
// rows: 4 row-tiles of 16. Per k-step: 4 A-frags + 8 W-frags -> 32 MFMA.
// C/D map (HW-confirmed r3 probe): row = quad*4 + reg, col = lane&15.
// ---------------------------------------------------------------------------
template <bool WB>
__global__ __launch_bounds__(256) void proj_kernel(
    const float* __restrict__ A,     // [M, 768] f32
    const void*  __restrict__ Wp,    // [512, 768] bf16 (WB) or f32 (!WB)
    const float* __restrict__ bias,  // [512] f32
    float* __restrict__ out,         // [M, 512] f32
    bf16_t* __restrict__ outb,       // [M, 512] bf16 mirror or nullptr
    int do_l2)
{
    const int tid  = threadIdx.x;
    const int wave = tid >> 6;
    const int lane = tid & 63;
    const int l16  = lane & 15;
    const int quad = lane >> 4;
    const int m0   = blockIdx.x * 64;
    const int e0   = wave * 128;
    const int K    = 768;

    f32x4 acc[4][8];
#pragma unroll
    for (int rt = 0; rt < 4; ++rt)
#pragma unroll
        for (int t = 0; t < 8; ++t) acc[rt][t] = (f32x4){0.f, 0.f, 0.f, 0.f};

    const float* arow[4];
#pragma unroll
    for (int rt = 0; rt < 4; ++rt)
        arow[rt] = A + (size_t)(m0 + rt * 16 + l16) * K + quad * 8;

    const bf16_t* wb = (const bf16_t*)Wp;
    const float*  wf = (const float*)Wp;

    for (int k0 = 0; k0 < K; k0 += 32) {
        bf16x8 af[4];
#pragma unroll
        for (int rt = 0; rt < 4; ++rt) af[rt] = cvt8(arow[rt] + k0);
#pragma unroll
        for (int t = 0; t < 8; ++t) {
            const size_t roff = (size_t)(e0 + t * 16 + l16) * K + quad * 8 + k0;
            bf16x8 bfv;
            if constexpr (WB) bfv = *reinterpret_cast<const bf16x8*>(wb + roff);
            else              bfv = cvt8(wf + roff);
#pragma unroll
            for (int rt = 0; rt < 4; ++rt)
                acc[rt][t] = MFMA16(af[rt], bfv, acc[rt][t]);
        }
    }

    // bias (per-column; lane's column = l16, fixed across regs)
#pragma unroll
    for (int t = 0; t < 8; ++t) {
        float bv = bias[e0 + t * 16 + l16];
#pragma unroll
        for (int rt = 0; rt < 4; ++rt)
#pragma unroll
            for (int r = 0; r < 4; ++r) acc[rt][t][r] += bv;
    }

    float inv[4][4];
#pragma unroll
    for (int rt = 0; rt < 4; ++rt)
#pragma unroll
        for (int r = 0; r < 4; ++r) inv[rt][r] = 1.f;

    __shared__ float sq[4][64];
    if (do_l2) {
#pragma unroll
        for (int rt = 0; rt < 4; ++rt)
#pragma unroll
            for (int r = 0; r < 4; ++r) {
                float s = 0.f;
#pragma unroll
                for (int t = 0; t < 8; ++t) s += acc[rt][t][r] * acc[rt][t][r];
                s += __shfl_xor(s, 1);
                s += __shfl_xor(s, 2);
                s += __shfl_xor(s, 4);
                s += __shfl_xor(s, 8);
                if (l16 == 0) sq[wave][rt * 16 + quad * 4 + r] = s;
            }
        __syncthreads();
#pragma unroll
        for (int rt = 0; rt < 4; ++rt)
#pragma unroll
            for (int r = 0; r < 4; ++r) {
                int row = rt * 16 + quad * 4 + r;
                float tot = sq[0][row] + sq[1][row] + sq[2][row] + sq[3][row];
                inv[rt][r] = 1.0f / fmaxf(sqrtf(tot), 1e-12f);
            }
    }

#pragma unroll
    for (int rt = 0; rt < 4; ++rt)
#pragma unroll
        for (int t = 0; t < 8; ++t)
#pragma unroll
            for (int r = 0; r < 4; ++r) {
                const size_t o = (size_t)(m0 + rt * 16 + quad * 4 + r) * 512
                               + (e0 + t * 16 + l16);
                float val = acc[rt][t][r] * inv[rt][r];
                out[o] = val;
                if (outb) outb[o] = (bf16_t)val;
            }
}

// ---------------------------------------------------------------------------
// MaxSim v2: block = (q, b-pair). S[t,v] = te[b,t,:] . ve[q,v,:].
// ve k-chunk (208 rows x 64 k, row stride 72 elems = 144 B -> conflict-free
// b128: bank-group = (l16+quad) mod 8) staged in LDS once, shared by 4 waves;
// each B-frag feeds 2 MFMAs (b0,b1). Wave w: t rows 16w..16w+15 of both b's.
// ---------------------------------------------------------------------------
template <bool BF>
__global__ __launch_bounds__(256) void maxsim_kernel(
    const void* __restrict__ te_,  // [128,64,512]
    const void* __restrict__ ve_,  // [128,196,512]
    float* __restrict__ sim)       // [128,128] (b major)
{
    const int tid  = threadIdx.x;
    const int wave = tid >> 6;
    const int lane = tid & 63;
    const int l16  = lane & 15;
    const int quad = lane >> 4;
    const int q    = blockIdx.x >> 6;
    const int bp   = blockIdx.x & 63;
    const int b0   = bp * 2;
    const int b1   = bp * 2 + 1;

    const bf16_t* teb = (const bf16_t*)te_;
    const float*  tef = (const float*)te_;
    const bf16_t* veb = (const bf16_t*)ve_;
    const float*  vef = (const float*)ve_;

    __shared__ bf16_t vs[208 * 72];          // 29952 B staging
    __shared__ float  maxt_s[2][4][208];
    __shared__ float  t2v_part[2][4];

    f32x4 acc0[13], acc1[13];
#pragma unroll
    for (int vt = 0; vt < 13; ++vt) {
        acc0[vt] = (f32x4){0.f, 0.f, 0.f, 0.f};
        acc1[vt] = (f32x4){0.f, 0.f, 0.f, 0.f};
    }

    const size_t toff0 = ((size_t)b0 * 64 + wave * 16 + l16) * 512 + quad * 8;
    const size_t toff1 = ((size_t)b1 * 64 + wave * 16 + l16) * 512 + quad * 8;

    for (int k0 = 0; k0 < 512; k0 += 64) {
        __syncthreads();  // protect previous chunk's reads
        // ---- stage ve[0..207][k0..k0+64) -> vs; 416 half-row segs of 64 B
        for (int s = tid; s < 416; s += 256) {
            const int row  = s >> 1;
            const int half = s & 1;
            const int vsrc = row < 196 ? row : 195;
            bf16_t* dst = &vs[row * 72 + half * 32];
            const size_t goff = ((size_t)q * 196 + vsrc) * 512 + k0 + half * 32;
            if constexpr (BF) {
#pragma unroll
                for (int j = 0; j < 4; ++j)
                    *reinterpret_cast<bf16x8*>(dst + j * 8) =
                        *reinterpret_cast<const bf16x8*>(veb + goff + j * 8);
            } else {
#pragma unroll
                for (int j = 0; j < 4; ++j)
                    *reinterpret_cast<bf16x8*>(dst + j * 8) = cvt8(vef + goff + j * 8);
            }
        }
        __syncthreads();
        // ---- compute: 2 k-steps x 13 v-tiles x 2 b's
#pragma unroll
        for (int ks = 0; ks < 2; ++ks) {
            bf16x8 a0, a1;
            if constexpr (BF) {
                a0 = *reinterpret_cast<const bf16x8*>(teb + toff0 + k0 + ks * 32);
                a1 = *reinterpret_cast<const bf16x8*>(teb + toff1 + k0 + ks * 32);
            } else {
                a0 = cvt8(tef + toff0 + k0 + ks * 32);
                a1 = cvt8(tef + toff1 + k0 + ks * 32);
            }
#pragma unroll
            for (int vt = 0; vt < 13; ++vt) {
                bf16x8 bv = *reinterpret_cast<const bf16x8*>(
                    &vs[(vt * 16 + l16) * 72 + ks * 32 + quad * 8]);
                acc0[vt] = MFMA16(a0, bv, acc0[vt]);
                acc1[vt] = MFMA16(a1, bv, acc1[vt]);
            }
        }
    }

    // ---- reductions (C/D map: row = quad*4+r, col = l16)
#pragma unroll
    for (int bi = 0; bi < 2; ++bi) {
        const f32x4* acc = bi ? acc1 : acc0;
        // t2v: per t-row max over v, then sum over this wave's 16 t's
        float sum_maxv = 0.f;
#pragma unroll
        for (int r = 0; r < 4; ++r) {
            float m = -3.0e38f;
#pragma unroll
            for (int vt = 0; vt < 13; ++vt) {
                int v = vt * 16 + l16;
                if (v < 196) m = fmaxf(m, acc[vt][r]);
            }
            m = fmaxf(m, __shfl_xor(m, 1));
            m = fmaxf(m, __shfl_xor(m, 2));
            m = fmaxf(m, __shfl_xor(m, 4));
            m = fmaxf(m, __shfl_xor(m, 8));
            sum_maxv += m;
        }
        sum_maxv += __shfl_xor(sum_maxv, 16);
        sum_maxv += __shfl_xor(sum_maxv, 32);
        if (lane == 0) t2v_part[bi][wave] = sum_maxv;
        // v2t: per v max over this wave's 16 t rows
#pragma unroll
        for (int vt = 0; vt < 13; ++vt) {
            float m = fmaxf(fmaxf(acc[vt][0], acc[vt][1]),
                            fmaxf(acc[vt][2], acc[vt][3]));
            m = fmaxf(m, __shfl_xor(m, 16));
            m = fmaxf(m, __shfl_xor(m, 32));
            if (lane < 16) maxt_s[bi][wave][vt * 16 + l16] = m;
        }
    }
    __syncthreads();

    if (wave == 0) {
#pragma unroll
        for (int bi = 0; bi < 2; ++bi) {
            float s_row = t2v_part[bi][0] + t2v_part[bi][1]
                        + t2v_part[bi][2] + t2v_part[bi][3];
            float s_col = 0.f;
            for (int v = lane; v < 196; v += 64) {
                float m = fmaxf(fmaxf(maxt_s[bi][0][v], maxt_s[bi][1][v]),
                                fmaxf(maxt_s[bi][2][v], maxt_s[bi][3][v]));
                s_col += m;
            }
            s_col += __shfl_xor(s_col, 1);
            s_col += __shfl_xor(s_col, 2);
            s_col += __shfl_xor(s_col, 4);
            s_col += __shfl_xor(s_col, 8);
            s_col += __shfl_xor(s_col, 16);
            s_col += __shfl_xor(s_col, 32);
            if (lane == 0) {
                float t2v = s_row * (1.0f / 196.0f);
                float v2t = s_col * (1.0f / 64.0f);
                sim[(size_t)(bp * 2 + bi) * 128 + q] = 0.5f * (t2v + v2t);
            }
        }
    }
}

// ---------------------------------------------------------------------------
// text_mask[b,t] = (t < len[b]), f32 out. Lengths 1..64 (never 0): int64
// storage shows hi-word==0 at odd i32 index -> auto-detect and stride.
// ---------------------------------------------------------------------------
__global__ void mask_kernel(const int* __restrict__ len, float* __restrict__ mask)
{
    int i = blockIdx.x * 256 + threadIdx.x;
    int is64 = (len[1] == 0) ? 1 : 0;
    if (i < 128 * 64) {
        int b = i >> 6;
        int t = i & 63;
        int L = is64 ? len[2 * b] : len[b];
        mask[i] = (t < L) ? 1.0f : 0.0f;
    }
}

extern "C" void kernel_launch(void* const* d_in, const int* in_sizes, int n_in,
                              void* d_out, int out_size, void* d_ws, size_t ws_size,
                              hipStream_t stream)
{
    // semantic -> d_in index; default = setup_inputs() dict order
    int idx[13] = {0, 1, 2, 3, 4, 5, 6, 7, 8, 9, 10, 11, 12};
    if (in_sizes && n_in >= 13) {
        bool dict = (in_sizes[2] == 19267584) && (in_sizes[4] == 393216);
        if (!dict) {
            static const int alpha_sizes[13] = {393216, 393216, 393216, 393216,
                                                512, 512, 512, 512, 128,
                                                98304, 6291456, 98304, 19267584};
            bool alpha = true;
            for (int i = 0; i < 13; ++i)
                if (in_sizes[i] != alpha_sizes[i]) { alpha = false; break; }
            if (alpha) {
                const int m[13] = {11, 9, 12, 10, 2, 6, 0, 4, 3, 7, 1, 5, 8};
                for (int i = 0; i < 13; ++i) idx[i] = m[i];
            }
        }
    }

    const float* visual_cls     = (const float*)d_in[idx[0]];
    const float* textual_cls    = (const float*)d_in[idx[1]];
    const float* visual_tokens  = (const float*)d_in[idx[2]];
    const float* textual_tokens = (const float*)d_in[idx[3]];
    const float* Wv_cls = (const float*)d_in[idx[4]];
    const float* bv_cls = (const float*)d_in[idx[5]];
    const float* Wt_cls = (const float*)d_in[idx[6]];
    const float* bt_cls = (const float*)d_in[idx[7]];
    const float* Wv_tok = (const float*)d_in[idx[8]];
    const float* bv_tok = (const float*)d_in[idx[9]];
    const float* Wt_tok = (const float*)d_in[idx[10]];
    const float* bt_tok = (const float*)d_in[idx[11]];
    const int*   text_length = (const int*)d_in[idx[12]];

    // f32 outputs, concatenated flat in return order
    float* out    = (float*)d_out;
    float* o_vcls = out;              // 128*512     = 65536
    float* o_tcls = out + 65536;      // 128*512     = 65536
    float* o_ve   = out + 131072;     // 128*196*512 = 12845056
    float* o_te   = out + 12976128;   // 128*64*512  = 4194304
    float* o_mask = out + 17170432;   // 128*64      = 8192
    float* o_sim  = out + 17178624;   // 128*128     = 16384

    const size_t WN  = (size_t)512 * 768;
    const size_t NVE = (size_t)12845056;
    const size_t NTE = (size_t)4194304;
    const bool ws_w   = ws_size >= 4 * WN * sizeof(bf16_t);
    const bool ws_big = ws_size >= (4 * WN + NVE + NTE) * sizeof(bf16_t);

    bf16_t* w0 = (bf16_t*)d_ws;
    bf16_t* w1 = w0 + WN;
    bf16_t* w2 = w1 + WN;
    bf16_t* w3 = w2 + WN;
    bf16_t* b_ve = ws_big ? (w3 + WN) : nullptr;
    bf16_t* b_te = ws_big ? (w3 + WN + NVE) : nullptr;

    dim3 blk(256);
    if (ws_w) {
        const int n4 = (int)(WN / 4);
        const int cvtg = (n4 + 255) / 256;
        cvt_f32_bf16<<<cvtg, blk, 0, stream>>>(Wv_cls, w0, n4);
        cvt_f32_bf16<<<cvtg, blk, 0, stream>>>(Wt_cls, w1, n4);
        cvt_f32_bf16<<<cvtg, blk, 0, stream>>>(Wv_tok, w2, n4);
        cvt_f32_bf16<<<cvtg, blk, 0, stream>>>(Wt_tok, w3, n4);

        proj_kernel<true><<<2,   blk, 0, stream>>>(visual_cls,  w0, bv_cls, o_vcls, nullptr, 0);
        proj_kernel<true><<<2,   blk, 0, stream>>>(textual_cls, w1, bt_cls, o_tcls, nullptr, 0);
        proj_kernel<true><<<392, blk, 0, stream>>>(visual_tokens,  w2, bv_tok, o_ve, b_ve, 1);
        proj_kernel<true><<<128, blk, 0, stream>>>(textual_tokens, w3, bt_tok, o_te, b_te, 1);
    } else {
        proj_kernel<false><<<2,   blk, 0, stream>>>(visual_cls,  Wv_cls, bv_cls, o_vcls, nullptr, 0);
        proj_kernel<false><<<2,   blk, 0, stream>>>(textual_cls, Wt_cls, bt_cls, o_tcls, nullptr, 0);
        proj_kernel<false><<<392, blk, 0, stream>>>(visual_tokens,  Wv_tok, bv_tok, o_ve, nullptr, 1);
        proj_kernel<false><<<128, blk, 0, stream>>>(textual_tokens, Wt_tok, bt_tok, o_te, nullptr, 1);
    }

    mask_kernel<<<32, blk, 0, stream>>>(text_length, o_mask);

    if (ws_big)
        maxsim_kernel<true><<<128 * 64, blk, 0, stream>>>(b_te, b_ve, o_sim);
    else
        maxsim_kernel<false><<<128 * 64, blk, 0, stream>>>(o_te, o_ve, o_sim);
}

// Round 7
// 740.591 us; speedup vs baseline: 2.7809x; 1.5231x over previous
//
#include <hip/hip_runtime.h>
#include <hip/hip_bf16.h>

typedef __bf16 bf16_t;
typedef __bf16 bf16x8 __attribute__((ext_vector_type(8)));
typedef __bf16 bf16x4 __attribute__((ext_vector_type(4)));
typedef float f32x4 __attribute__((ext_vector_type(4)));

#define MFMA16(a, b, c) __builtin_amdgcn_mfma_f32_16x16x32_bf16((a), (b), (c), 0, 0, 0)

// load 8 consecutive f32, round to bf16x8 (RNE)
__device__ inline bf16x8 cvt8(const float* __restrict__ p) {
    f32x4 a = *reinterpret_cast<const f32x4*>(p);
    f32x4 b = *reinterpret_cast<const f32x4*>(p + 4);
    bf16x8 r;
    r[0] = (bf16_t)a[0]; r[1] = (bf16_t)a[1]; r[2] = (bf16_t)a[2]; r[3] = (bf16_t)a[3];
    r[4] = (bf16_t)b[0]; r[5] = (bf16_t)b[1]; r[6] = (bf16_t)b[2]; r[7] = (bf16_t)b[3];
    return r;
}

// async global->LDS DMA, 16 B per lane; LDS dest = wave-uniform base + lane*16
__device__ __forceinline__ void gload_lds16(const bf16_t* g, bf16_t* l) {
    __builtin_amdgcn_global_load_lds(
        (const __attribute__((address_space(1))) void*)g,
        (__attribute__((address_space(3))) void*)l, 16, 0, 0);
}

// ---------------------------------------------------------------------------
// f32 -> bf16 elementwise, 4 elems/thread
// ---------------------------------------------------------------------------
__global__ __launch_bounds__(256) void cvt_f32_bf16(
    const float* __restrict__ in, bf16_t* __restrict__ out, int n4)
{
    int i = blockIdx.x * 256 + threadIdx.x;
    if (i < n4) {
        f32x4 v = reinterpret_cast<const f32x4*>(in)[i];
        bf16x4 r;
        r[0] = (bf16_t)v[0]; r[1] = (bf16_t)v[1];
        r[2] = (bf16_t)v[2]; r[3] = (bf16_t)v[3];
        reinterpret_cast<bf16x4*>(out)[i] = r;
    }
}

// ---------------------------------------------------------------------------
// Projection: out[M,512] = bf16(X[M,768]) @ bf16(W[512,768])^T + bias,
// optional row L2-norm. f32 out + optional bf16 mirror.
// Block = 256 thr (4 waves) = 64 rows x 512 cols; wave w: cols w*128..+127.
// C/D map (HW-confirmed): row = quad*4 + reg, col = lane&15.
// WB: W is bf16; AB: A is bf16 (pre-converted in ws).
// ---------------------------------------------------------------------------
template <bool WB, bool AB>
__global__ __launch_bounds__(256) void proj_kernel(
    const void* __restrict__ Ap,     // [M, 768] f32 or bf16
    const void* __restrict__ Wp,     // [512, 768] bf16 (WB) or f32 (!WB)
    const float* __restrict__ bias,  // [512] f32
    float* __restrict__ out,         // [M, 512] f32
    bf16_t* __restrict__ outb,       // [M, 512] bf16 mirror or nullptr
    int do_l2)
{
    const int tid  = threadIdx.x;
    const int wave = tid >> 6;
    const int lane = tid & 63;
    const int l16  = lane & 15;
    const int quad = lane >> 4;
    const int m0   = blockIdx.x * 64;
    const int e0   = wave * 128;
    const int K    = 768;

    f32x4 acc[4][8];
#pragma unroll
    for (int rt = 0; rt < 4; ++rt)
#pragma unroll
        for (int t = 0; t < 8; ++t) acc[rt][t] = (f32x4){0.f, 0.f, 0.f, 0.f};

    const float*  arf[4];
    const bf16_t* arb[4];
#pragma unroll
    for (int rt = 0; rt < 4; ++rt) {
        size_t off = (size_t)(m0 + rt * 16 + l16) * K + quad * 8;
        arf[rt] = (const float*)Ap + off;
        arb[rt] = (const bf16_t*)Ap + off;
    }

    const bf16_t* wb = (const bf16_t*)Wp;
    const float*  wf = (const float*)Wp;

    for (int k0 = 0; k0 < K; k0 += 32) {
        bf16x8 af[4];
#pragma unroll
        for (int rt = 0; rt < 4; ++rt) {
            if constexpr (AB) af[rt] = *reinterpret_cast<const bf16x8*>(arb[rt] + k0);
            else              af[rt] = cvt8(arf[rt] + k0);
        }
#pragma unroll
        for (int t = 0; t < 8; ++t) {
            const size_t roff = (size_t)(e0 + t * 16 + l16) * K + quad * 8 + k0;
            bf16x8 bfv;
            if constexpr (WB) bfv = *reinterpret_cast<const bf16x8*>(wb + roff);
            else              bfv = cvt8(wf + roff);
#pragma unroll
            for (int rt = 0; rt < 4; ++rt)
                acc[rt][t] = MFMA16(af[rt], bfv, acc[rt][t]);
        }
    }

#pragma unroll
    for (int t = 0; t < 8; ++t) {
        float bv = bias[e0 + t * 16 + l16];
#pragma unroll
        for (int rt = 0; rt < 4; ++rt)
#pragma unroll
            for (int r = 0; r < 4; ++r) acc[rt][t][r] += bv;
    }

    float inv[4][4];
#pragma unroll
    for (int rt = 0; rt < 4; ++rt)
#pragma unroll
        for (int r = 0; r < 4; ++r) inv[rt][r] = 1.f;

    __shared__ float sq[4][64];
    if (do_l2) {
#pragma unroll
        for (int rt = 0; rt < 4; ++rt)
#pragma unroll
            for (int r = 0; r < 4; ++r) {
                float s = 0.f;
#pragma unroll
                for (int t = 0; t < 8; ++t) s += acc[rt][t][r] * acc[rt][t][r];
                s += __shfl_xor(s, 1);
                s += __shfl_xor(s, 2);
                s += __shfl_xor(s, 4);
                s += __shfl_xor(s, 8);
                if (l16 == 0) sq[wave][rt * 16 + quad * 4 + r] = s;
            }
        __syncthreads();
#pragma unroll
        for (int rt = 0; rt < 4; ++rt)
#pragma unroll
            for (int r = 0; r < 4; ++r) {
                int row = rt * 16 + quad * 4 + r;
                float tot = sq[0][row] + sq[1][row] + sq[2][row] + sq[3][row];
                inv[rt][r] = 1.0f / fmaxf(sqrtf(tot), 1e-12f);
            }
    }

#pragma unroll
    for (int rt = 0; rt < 4; ++rt)
#pragma unroll
        for (int t = 0; t < 8; ++t)
#pragma unroll
            for (int r = 0; r < 4; ++r) {
                const size_t o = (size_t)(m0 + rt * 16 + quad * 4 + r) * 512
                               + (e0 + t * 16 + l16);
                float val = acc[rt][t][r] * inv[rt][r];
                out[o] = val;
                if (outb) outb[o] = (bf16_t)val;
            }
}

// ---------------------------------------------------------------------------
// MaxSim v3 (DMA): block = (q, b-pair). S[t,v] = te[b,t,:] . ve[q,v,:].
// ve k-chunks (208 rows x 64 k) staged via global_load_lds into a double-
// buffered XOR-swizzled LDS tile: row-major [208][8 segs of 16B], phys seg =
// logical ^ (row&7). DMA lane map: row = 8g+(l>>3), fetches logical seg
// (l&7)^(l>>3) -> a permutation inside each row's 128 B (coalesced) landing
// at LDS base + l*16. Reads: phys = (ks*4+quad)^(l16&7) -> 2-way floor only.
// One barrier per chunk; next chunk's DMA issued right after the barrier.
// ---------------------------------------------------------------------------
__global__ __launch_bounds__(256) void maxsim_dma(
    const bf16_t* __restrict__ te,  // [128,64,512] bf16
    const bf16_t* __restrict__ ve,  // [128,196,512] bf16
    float* __restrict__ sim)        // [128,128] (b major)
{
    const int tid  = threadIdx.x;
    const int wave = tid >> 6;
    const int lane = tid & 63;
    const int l16  = lane & 15;
    const int quad = lane >> 4;
    const int q    = blockIdx.x >> 6;
    const int bp   = blockIdx.x & 63;

    __shared__ bf16_t vs[2][208 * 64];      // 2 x 26624 B
    __shared__ float  maxt_s[2][4][208];
    __shared__ float  t2v_part[2][4];

    f32x4 acc0[13], acc1[13];
#pragma unroll
    for (int vt = 0; vt < 13; ++vt) {
        acc0[vt] = (f32x4){0.f, 0.f, 0.f, 0.f};
        acc1[vt] = (f32x4){0.f, 0.f, 0.f, 0.f};
    }

    const size_t toff0 = ((size_t)(bp * 2) * 64 + wave * 16 + l16) * 512 + quad * 8;
    const size_t toff1 = toff0 + (size_t)64 * 512;

    auto issue_chunk = [&](int buf, int k0) {
        for (int g = wave; g < 26; g += 4) {       // 8 rows per DMA instr
            int row  = 8 * g + (lane >> 3);
            int srow = row < 196 ? row : 195;      // clamp; masked later
            int seg  = (lane & 7) ^ (lane >> 3);   // logical seg for this slot
            const bf16_t* gp = ve + ((size_t)q * 196 + srow) * 512 + k0 + seg * 8;
            gload_lds16(gp, &vs[buf][g * 512]);
        }
    };

    issue_chunk(0, 0);
#pragma unroll
    for (int c = 0; c < 8; ++c) {
        __syncthreads();                       // DMA for buf c&1 complete
        if (c < 7) issue_chunk((c + 1) & 1, (c + 1) * 64);
        const int buf = c & 1;
        bf16x8 a0[2], a1[2];
#pragma unroll
        for (int ks = 0; ks < 2; ++ks) {
            a0[ks] = *reinterpret_cast<const bf16x8*>(te + toff0 + c * 64 + ks * 32);
            a1[ks] = *reinterpret_cast<const bf16x8*>(te + toff1 + c * 64 + ks * 32);
        }
#pragma unroll
        for (int ks = 0; ks < 2; ++ks) {
#pragma unroll
            for (int vt = 0; vt < 13; ++vt) {
                const int row  = vt * 16 + l16;
                const int phys = (ks * 4 + quad) ^ (l16 & 7);
                bf16x8 bv = *reinterpret_cast<const bf16x8*>(&vs[buf][row * 64 + phys * 8]);
                acc0[vt] = MFMA16(a0[ks], bv, acc0[vt]);
                acc1[vt] = MFMA16(a1[ks], bv, acc1[vt]);
            }
        }
    }

    // ---- reductions (C/D map: row = quad*4+r, col = l16)
#pragma unroll
    for (int bi = 0; bi < 2; ++bi) {
        const f32x4* acc = bi ? acc1 : acc0;
        float sum_maxv = 0.f;
#pragma unroll
        for (int r = 0; r < 4; ++r) {
            float m = -3.0e38f;
#pragma unroll
            for (int vt = 0; vt < 13; ++vt) {
                int v = vt * 16 + l16;
                if (v < 196) m = fmaxf(m, acc[vt][r]);
            }
            m = fmaxf(m, __shfl_xor(m, 1));
            m = fmaxf(m, __shfl_xor(m, 2));
            m = fmaxf(m, __shfl_xor(m, 4));
            m = fmaxf(m, __shfl_xor(m, 8));
            sum_maxv += m;
        }
        sum_maxv += __shfl_xor(sum_maxv, 16);
        sum_maxv += __shfl_xor(sum_maxv, 32);
        if (lane == 0) t2v_part[bi][wave] = sum_maxv;
#pragma unroll
        for (int vt = 0; vt < 13; ++vt) {
            float m = fmaxf(fmaxf(acc[vt][0], acc[vt][1]),
                            fmaxf(acc[vt][2], acc[vt][3]));
            m = fmaxf(m, __shfl_xor(m, 16));
            m = fmaxf(m, __shfl_xor(m, 32));
            if (lane < 16) maxt_s[bi][wave][vt * 16 + l16] = m;
        }
    }
    __syncthreads();

    if (wave == 0) {
#pragma unroll
        for (int bi = 0; bi < 2; ++bi) {
            float s_row = t2v_part[bi][0] + t2v_part[bi][1]
                        + t2v_part[bi][2] + t2v_part[bi][3];
            float s_col = 0.f;
            for (int v = lane; v < 196; v += 64) {
                float m = fmaxf(fmaxf(maxt_s[bi][0][v], maxt_s[bi][1][v]),
                                fmaxf(maxt_s[bi][2][v], maxt_s[bi][3][v]));
                s_col += m;
            }
            s_col += __shfl_xor(s_col, 1);
            s_col += __shfl_xor(s_col, 2);
            s_col += __shfl_xor(s_col, 4);
            s_col += __shfl_xor(s_col, 8);
            s_col += __shfl_xor(s_col, 16);
            s_col += __shfl_xor(s_col, 32);
            if (lane == 0) {
                float t2v = s_row * (1.0f / 196.0f);
                float v2t = s_col * (1.0f / 64.0f);
                sim[(size_t)(bp * 2 + bi) * 128 + q] = 0.5f * (t2v + v2t);
            }
        }
    }
}

// ---------------------------------------------------------------------------
// Fallback maxsim (f32 operands from d_out, manual staging) — correctness path
// used only when ws is too small for the bf16 mirrors.
// ---------------------------------------------------------------------------
__global__ __launch_bounds__(256) void maxsim_fb(
    const float* __restrict__ te, const float* __restrict__ ve,
    float* __restrict__ sim)
{
    const int tid  = threadIdx.x;
    const int wave = tid >> 6;
    const int lane = tid & 63;
    const int l16  = lane & 15;
    const int quad = lane >> 4;
    const int q    = blockIdx.x >> 6;
    const int bp   = blockIdx.x & 63;

    __shared__ bf16_t vsl[208 * 72];
    __shared__ float  maxt_s[2][4][208];
    __shared__ float  t2v_part[2][4];

    f32x4 acc0[13], acc1[13];
#pragma unroll
    for (int vt = 0; vt < 13; ++vt) {
        acc0[vt] = (f32x4){0.f, 0.f, 0.f, 0.f};
        acc1[vt] = (f32x4){0.f, 0.f, 0.f, 0.f};
    }
    const size_t toff0 = ((size_t)(bp * 2) * 64 + wave * 16 + l16) * 512 + quad * 8;
    const size_t toff1 = toff0 + (size_t)64 * 512;

    for (int k0 = 0; k0 < 512; k0 += 64) {
        __syncthreads();
        for (int s = tid; s < 416; s += 256) {
            const int row  = s >> 1;
            const int half = s & 1;
            const int vsrc = row < 196 ? row : 195;
            bf16x8 tmp[4];
            const size_t goff = ((size_t)q * 196 + vsrc) * 512 + k0 + half * 32;
#pragma unroll
            for (int j = 0; j < 4; ++j) tmp[j] = cvt8(ve + goff + j * 8);
            bf16_t* dst = &vsl[row * 72 + half * 32];
#pragma unroll
            for (int j = 0; j < 4; ++j)
                *reinterpret_cast<bf16x8*>(dst + j * 8) = tmp[j];
        }
        __syncthreads();
#pragma unroll
        for (int ks = 0; ks < 2; ++ks) {
            bf16x8 a0 = cvt8(te + toff0 + k0 + ks * 32);
            bf16x8 a1 = cvt8(te + toff1 + k0 + ks * 32);
#pragma unroll
            for (int vt = 0; vt < 13; ++vt) {
                bf16x8 bv = *reinterpret_cast<const bf16x8*>(
                    &vsl[(vt * 16 + l16) * 72 + ks * 32 + quad * 8]);
                acc0[vt] = MFMA16(a0, bv, acc0[vt]);
                acc1[vt] = MFMA16(a1, bv, acc1[vt]);
            }
        }
    }

#pragma unroll
    for (int bi = 0; bi < 2; ++bi) {
        const f32x4* acc = bi ? acc1 : acc0;
        float sum_maxv = 0.f;
#pragma unroll
        for (int r = 0; r < 4; ++r) {
            float m = -3.0e38f;
#pragma unroll
            for (int vt = 0; vt < 13; ++vt) {
                int v = vt * 16 + l16;
                if (v < 196) m = fmaxf(m, acc[vt][r]);
            }
            m = fmaxf(m, __shfl_xor(m, 1));
            m = fmaxf(m, __shfl_xor(m, 2));
            m = fmaxf(m, __shfl_xor(m, 4));
            m = fmaxf(m, __shfl_xor(m, 8));
            sum_maxv += m;
        }
        sum_maxv += __shfl_xor(sum_maxv, 16);
        sum_maxv += __shfl_xor(sum_maxv, 32);
        if (lane == 0) t2v_part[bi][wave] = sum_maxv;
#pragma unroll
        for (int vt = 0; vt < 13; ++vt) {
            float m = fmaxf(fmaxf(acc[vt][0], acc[vt][1]),
                            fmaxf(acc[vt][2], acc[vt][3]));
            m = fmaxf(m, __shfl_xor(m, 16));
            m = fmaxf(m, __shfl_xor(m, 32));
            if (lane < 16) maxt_s[bi][wave][vt * 16 + l16] = m;
        }
    }
    __syncthreads();
    if (wave == 0) {
#pragma unroll
        for (int bi = 0; bi < 2; ++bi) {
            float s_row = t2v_part[bi][0] + t2v_part[bi][1]
                        + t2v_part[bi][2] + t2v_part[bi][3];
            float s_col = 0.f;
            for (int v = lane; v < 196; v += 64) {
                float m = fmaxf(fmaxf(maxt_s[bi][0][v], maxt_s[bi][1][v]),
                                fmaxf(maxt_s[bi][2][v], maxt_s[bi][3][v]));
                s_col += m;
            }
            s_col += __shfl_xor(s_col, 1);
            s_col += __shfl_xor(s_col, 2);
            s_col += __shfl_xor(s_col, 4);
            s_col += __shfl_xor(s_col, 8);
            s_col += __shfl_xor(s_col, 16);
            s_col += __shfl_xor(s_col, 32);
            if (lane == 0)
                sim[(size_t)(bp * 2 + bi) * 128 + q] =
                    0.5f * (s_row * (1.0f / 196.0f) + s_col * (1.0f / 64.0f));
        }
    }
}

// ---------------------------------------------------------------------------
// text_mask[b,t] = (t < len[b]); int64-vs-int32 auto-detect (lengths 1..64).
// ---------------------------------------------------------------------------
__global__ void mask_kernel(const int* __restrict__ len, float* __restrict__ mask)
{
    int i = blockIdx.x * 256 + threadIdx.x;
    int is64 = (len[1] == 0) ? 1 : 0;
    if (i < 128 * 64) {
        int b = i >> 6;
        int t = i & 63;
        int L = is64 ? len[2 * b] : len[b];
        mask[i] = (t < L) ? 1.0f : 0.0f;
    }
}

extern "C" void kernel_launch(void* const* d_in, const int* in_sizes, int n_in,
                              void* d_out, int out_size, void* d_ws, size_t ws_size,
                              hipStream_t stream)
{
    int idx[13] = {0, 1, 2, 3, 4, 5, 6, 7, 8, 9, 10, 11, 12};
    if (in_sizes && n_in >= 13) {
        bool dict = (in_sizes[2] == 19267584) && (in_sizes[4] == 393216);
        if (!dict) {
            static const int alpha_sizes[13] = {393216, 393216, 393216, 393216,
                                                512, 512, 512, 512, 128,
                                                98304, 6291456, 98304, 19267584};
            bool alpha = true;
            for (int i = 0; i < 13; ++i)
                if (in_sizes[i] != alpha_sizes[i]) { alpha = false; break; }
            if (alpha) {
                const int m[13] = {11, 9, 12, 10, 2, 6, 0, 4, 3, 7, 1, 5, 8};
                for (int i = 0; i < 13; ++i) idx[i] = m[i];
            }
        }
    }

    const float* visual_cls     = (const float*)d_in[idx[0]];
    const float* textual_cls    = (const float*)d_in[idx[1]];
    const float* visual_tokens  = (const float*)d_in[idx[2]];
    const float* textual_tokens = (const float*)d_in[idx[3]];
    const float* Wv_cls = (const float*)d_in[idx[4]];
    const float* bv_cls = (const float*)d_in[idx[5]];
    const float* Wt_cls = (const float*)d_in[idx[6]];
    const float* bt_cls = (const float*)d_in[idx[7]];
    const float* Wv_tok = (const float*)d_in[idx[8]];
    const float* bv_tok = (const float*)d_in[idx[9]];
    const float* Wt_tok = (const float*)d_in[idx[10]];
    const float* bt_tok = (const float*)d_in[idx[11]];
    const int*   text_length = (const int*)d_in[idx[12]];

    float* out    = (float*)d_out;
    float* o_vcls = out;
    float* o_tcls = out + 65536;
    float* o_ve   = out + 131072;
    float* o_te   = out + 12976128;
    float* o_mask = out + 17170432;
    float* o_sim  = out + 17178624;

    const size_t WN  = 393216;     // per-weight elems
    const size_t NVE = 12845056;   // ve elems
    const size_t NTE = 4194304;    // te elems
    const size_t NVT = 19267584;   // visual_tokens elems
    const size_t NTT = 6291456;    // textual_tokens elems
    const bool ws_w   = ws_size >= 4 * WN * 2;
    const bool ws_big = ws_size >= (4 * WN + NVE + NTE) * 2;
    const bool ws_tok = ws_size >= (4 * WN + NVE + NTE + NVT + NTT) * 2;

    bf16_t* w0   = (bf16_t*)d_ws;
    bf16_t* w1   = w0 + WN;
    bf16_t* w2   = w1 + WN;
    bf16_t* w3   = w2 + WN;
    bf16_t* b_ve = w3 + WN;
    bf16_t* b_te = b_ve + NVE;
    bf16_t* vt_b = b_te + NTE;
    bf16_t* tt_b = vt_b + NVT;

    dim3 blk(256);
    if (ws_w) {
        const int n4w = (int)(WN / 4);
        cvt_f32_bf16<<<(n4w + 255) / 256, blk, 0, stream>>>(Wv_cls, w0, n4w);
        cvt_f32_bf16<<<(n4w + 255) / 256, blk, 0, stream>>>(Wt_cls, w1, n4w);
        cvt_f32_bf16<<<(n4w + 255) / 256, blk, 0, stream>>>(Wv_tok, w2, n4w);
        cvt_f32_bf16<<<(n4w + 255) / 256, blk, 0, stream>>>(Wt_tok, w3, n4w);

        proj_kernel<true, false><<<2, blk, 0, stream>>>(visual_cls,  w0, bv_cls, o_vcls, nullptr, 0);
        proj_kernel<true, false><<<2, blk, 0, stream>>>(textual_cls, w1, bt_cls, o_tcls, nullptr, 0);

        if (ws_tok) {
            cvt_f32_bf16<<<(int)(NVT / 4 + 255) / 256, blk, 0, stream>>>(visual_tokens,  vt_b, (int)(NVT / 4));
            cvt_f32_bf16<<<(int)(NTT / 4 + 255) / 256, blk, 0, stream>>>(textual_tokens, tt_b, (int)(NTT / 4));
            proj_kernel<true, true><<<392, blk, 0, stream>>>(vt_b, w2, bv_tok, o_ve,
                                                             ws_big ? b_ve : nullptr, 1);
            proj_kernel<true, true><<<128, blk, 0, stream>>>(tt_b, w3, bt_tok, o_te,
                                                             ws_big ? b_te : nullptr, 1);
        } else {
            proj_kernel<true, false><<<392, blk, 0, stream>>>(visual_tokens,  w2, bv_tok, o_ve,
                                                              ws_big ? b_ve : nullptr, 1);
            proj_kernel<true, false><<<128, blk, 0, stream>>>(textual_tokens, w3, bt_tok, o_te,
                                                              ws_big ? b_te : nullptr, 1);
        }
    } else {
        proj_kernel<false, false><<<2, blk, 0, stream>>>(visual_cls,  Wv_cls, bv_cls, o_vcls, nullptr, 0);
        proj_kernel<false, false><<<2, blk, 0, stream>>>(textual_cls, Wt_cls, bt_cls, o_tcls, nullptr, 0);
        proj_kernel<false, false><<<392, blk, 0, stream>>>(visual_tokens,  Wv_tok, bv_tok, o_ve, nullptr, 1);
        proj_kernel<false, false><<<128, blk, 0, stream>>>(textual_tokens, Wt_tok, bt_tok, o_te, nullptr, 1);
    }

    mask_kernel<<<32, blk, 0, stream>>>(text_length, o_mask);

    if (ws_big)
        maxsim_dma<<<128 * 64, blk, 0, stream>>>(b_te, b_ve, o_sim);
    else
        maxsim_fb<<<128 * 64, blk, 0, stream>>>(o_te, o_ve, o_sim);
}